// Round 2
// baseline (191.559 us; speedup 1.0000x reference)
//
#include <hip/hip_runtime.h>
#include <hip/hip_bf16.h>

#define LN_EPS 1e-5f

// ---------------------------------------------------------------------------
// ws layout (floats):
//   [0, N*32)        sum accumulators (scatter of per-edge contrib @ Wout)
//   [N*32, N*33)     counts
//   then: flag (1), pad (7), coef (4*10), M (4*3*32), cvo (4*32)
// ---------------------------------------------------------------------------

// Detect int64 edge_index layout: odd 32-bit words of the first 8 values
// (random in [0,1e5)) are all zero iff the buffer is little-endian int64.
__global__ void precompute_kernel(const float* __restrict__ Wq,
                                  const float* __restrict__ bq,
                                  const float* __restrict__ Wk,
                                  const float* __restrict__ bk,
                                  const float* __restrict__ Wv,
                                  const float* __restrict__ bv,
                                  const float* __restrict__ Wout,
                                  const int* __restrict__ ei,
                                  float* __restrict__ flag,
                                  float* __restrict__ coef,
                                  float* __restrict__ M,
                                  float* __restrict__ cvo) {
  int t = threadIdx.x;
  const float scale = 0.17677669529663687f;  // 1/sqrt(32)

  if (t == 0) {
    int all_zero = 1;
    for (int i = 0; i < 8; ++i) all_zero &= (ei[2 * i + 1] == 0);
    flag[0] = all_zero ? 1.0f : 0.0f;
  }

  if (t < 128) {
    int h = t >> 5, o = t & 31;
    float m0 = 0, m1 = 0, m2 = 0, cv = 0;
    for (int d = 0; d < 32; ++d) {
      int j = h * 32 + d;
      float w = Wout[j * 32 + o];
      m0 += Wv[0 * 128 + j] * w;
      m1 += Wv[1 * 128 + j] * w;
      m2 += Wv[2 * 128 + j] * w;
      cv += bv[j] * w;
    }
    M[(h * 3 + 0) * 32 + o] = m0;
    M[(h * 3 + 1) * 32 + o] = m1;
    M[(h * 3 + 2) * 32 + o] = m2;
    cvo[h * 32 + o] = cv;
  }

  if (t < 40) {
    int h = t / 10, j = t % 10;
    float acc = 0;
    for (int d = 0; d < 32; ++d) {
      int idx = h * 32 + d;
      float q0 = Wq[0 * 128 + idx], q1 = Wq[1 * 128 + idx], q2 = Wq[2 * 128 + idx];
      float k0 = Wk[0 * 128 + idx], k1 = Wk[1 * 128 + idx], k2 = Wk[2 * 128 + idx];
      float bqv = bq[idx], bkv = bk[idx];
      float v;
      switch (j) {
        case 0: v = q0 * k0; break;                 // x*x
        case 1: v = q1 * k1; break;                 // y*y
        case 2: v = q2 * k2; break;                 // z*z
        case 3: v = q0 * k1 + q1 * k0; break;       // x*y
        case 4: v = q0 * k2 + q2 * k0; break;       // x*z
        case 5: v = q1 * k2 + q2 * k1; break;       // y*z
        case 6: v = q0 * bkv + k0 * bqv; break;     // x
        case 7: v = q1 * bkv + k1 * bqv; break;     // y
        case 8: v = q2 * bkv + k2 * bqv; break;     // z
        default: v = bqv * bkv; break;              // const
      }
      acc += v;
    }
    coef[h * 10 + j] = acc * scale;
  }
}

__global__ void edge_kernel(const float* __restrict__ pos,
                            const int* __restrict__ ei, int E, int N,
                            const float* __restrict__ flag,
                            const float* __restrict__ coef,
                            const float* __restrict__ M,
                            const float* __restrict__ cvo,
                            float* __restrict__ sums,
                            float* __restrict__ cnts) {
  const int lane = threadIdx.x & 31;
  const int group = (blockIdx.x * blockDim.x + threadIdx.x) >> 5;
  const int base = group * 32;
  if (base >= E) return;

  const int i64 = (flag[0] != 0.0f) ? 1 : 0;

  // per-lane output-column slice of the folded V@Wout matrices (registers)
  float m[12], cw[4];
#pragma unroll
  for (int h = 0; h < 4; ++h) {
    cw[h] = cvo[h * 32 + lane];
#pragma unroll
    for (int i = 0; i < 3; ++i) m[h * 3 + i] = M[(h * 3 + i) * 32 + lane];
  }

  const int valid_n = min(32, E - base);
  const int e = base + lane;
  const bool valid = lane < valid_n;

  int c = 0;
  float rx = 0, ry = 0, rz = 0;
  float a0 = 0, a1 = 0, a2 = 0, a3 = 0;
  if (valid) {
    int r, cc;
    if (i64) {
      r = ei[2 * (size_t)e];
      cc = ei[2 * ((size_t)E + e)];
    } else {
      r = ei[e];
      cc = ei[E + e];
    }
    c = cc;
    rx = pos[r * 3 + 0] - pos[c * 3 + 0];
    ry = pos[r * 3 + 1] - pos[c * 3 + 1];
    rz = pos[r * 3 + 2] - pos[c * 3 + 2];
    float s[4];
#pragma unroll
    for (int h = 0; h < 4; ++h) {
      const float* cf = coef + h * 10;
      s[h] = cf[9] + rx * cf[6] + ry * cf[7] + rz * cf[8] + rx * rx * cf[0] +
             ry * ry * cf[1] + rz * rz * cf[2] + rx * ry * cf[3] +
             rx * rz * cf[4] + ry * rz * cf[5];
    }
    float mx = fmaxf(fmaxf(s[0], s[1]), fmaxf(s[2], s[3]));
    float e0 = __expf(s[0] - mx), e1 = __expf(s[1] - mx);
    float e2 = __expf(s[2] - mx), e3 = __expf(s[3] - mx);
    float inv = 1.0f / (e0 + e1 + e2 + e3);
    a0 = e0 * inv; a1 = e1 * inv; a2 = e2 * inv; a3 = e3 * inv;
    atomicAdd(&cnts[c], 1.0f);
  }

  for (int t = 0; t < valid_n; ++t) {
    float tx = __shfl(rx, t, 32);
    float ty = __shfl(ry, t, 32);
    float tz = __shfl(rz, t, 32);
    float b0 = __shfl(a0, t, 32);
    float b1 = __shfl(a1, t, 32);
    float b2_ = __shfl(a2, t, 32);
    float b3 = __shfl(a3, t, 32);
    int ct = __shfl(c, t, 32);
    float acc = b0 * (cw[0] + tx * m[0] + ty * m[1] + tz * m[2]) +
                b1 * (cw[1] + tx * m[3] + ty * m[4] + tz * m[5]) +
                b2_ * (cw[2] + tx * m[6] + ty * m[7] + tz * m[8]) +
                b3 * (cw[3] + tx * m[9] + ty * m[10] + tz * m[11]);
    atomicAdd(&sums[(size_t)ct * 32 + lane], acc);
  }
}

__global__ void node_kernel(const float* __restrict__ sums,
                            const float* __restrict__ cnts,
                            const float* __restrict__ bout,
                            const float* __restrict__ gamma,
                            const float* __restrict__ beta,
                            float* __restrict__ out, int N) {
  int tid = blockIdx.x * blockDim.x + threadIdx.x;
  int node = tid >> 5;
  int d = tid & 31;
  if (node >= N) return;

  float s = sums[(size_t)node * 32 + d];
  float cnt = cnts[node];
  float val = s / fmaxf(cnt, 1.0f) + bout[d];

  float sx = val, sx2 = val * val;
#pragma unroll
  for (int off = 16; off >= 1; off >>= 1) {
    sx += __shfl_xor(sx, off);
    sx2 += __shfl_xor(sx2, off);
  }
  float mu = sx * (1.0f / 32.0f);
  float var = sx2 * (1.0f / 32.0f) - mu * mu;
  float inv = rsqrtf(var + LN_EPS);
  float y = (val - mu) * inv * gamma[d] + beta[d];
  float o = y * (1.0f / (1.0f + __expf(-y)));  // SiLU
  out[(size_t)node * 32 + d] = o;
}

extern "C" void kernel_launch(void* const* d_in, const int* in_sizes, int n_in,
                              void* d_out, int out_size, void* d_ws, size_t ws_size,
                              hipStream_t stream) {
  const float* pos  = (const float*)d_in[0];
  const int*   ei   = (const int*)d_in[1];
  const float* Wq   = (const float*)d_in[2];
  const float* bq   = (const float*)d_in[3];
  const float* Wk   = (const float*)d_in[4];
  const float* bk   = (const float*)d_in[5];
  const float* Wv   = (const float*)d_in[6];
  const float* bv   = (const float*)d_in[7];
  const float* Wout = (const float*)d_in[8];
  const float* bout = (const float*)d_in[9];
  const float* gam  = (const float*)d_in[10];
  const float* bet  = (const float*)d_in[11];

  const int N = in_sizes[0] / 3;
  const int E = in_sizes[1] / 2;

  float* ws   = (float*)d_ws;
  float* sums = ws;                          // N*32
  float* cnts = sums + (size_t)N * 32;       // N
  float* flag = cnts + N;                    // 1 (+7 pad)
  float* coef = flag + 8;                    // 40
  float* M    = coef + 40;                   // 384
  float* cvo  = M + 384;                     // 128

  hipMemsetAsync(d_ws, 0, ((size_t)N * 32 + N) * sizeof(float), stream);

  precompute_kernel<<<1, 128, 0, stream>>>(Wq, bq, Wk, bk, Wv, bv, Wout, ei,
                                           flag, coef, M, cvo);

  int edge_blocks = (E + 255) / 256;  // 8 groups of 32 lanes per block
  edge_kernel<<<edge_blocks, 256, 0, stream>>>(pos, ei, E, N, flag, coef, M, cvo,
                                               sums, cnts);

  int node_blocks = ((size_t)N * 32 + 255) / 256;
  node_kernel<<<node_blocks, 256, 0, stream>>>(sums, cnts, bout, gam, bet,
                                               (float*)d_out, N);

  (void)n_in; (void)out_size; (void)ws_size;
}

// Round 3
// 145.611 us; speedup vs baseline: 1.3156x; 1.3156x over previous
//
#include <hip/hip_runtime.h>
#include <hip/hip_bf16.h>

#define LN_EPS 1e-5f

// ---------------------------------------------------------------------------
// Algebra: per-edge contribution to the (pre-mean) node feature is
//   contrib[col] = sum_h a_h (rel . M_h[col] + cv_h[col])
// which is linear in f = (a0,a1,a2, rx,ry,rz, a_h*rel_i for h<3, 1)  [16 dims]
// using sum_h a_h = 1 and a3*rel_i = rel_i - sum_{h<3} a_h rel_i.
// So scatter-mean(contrib) = scatter-mean(f) @ T, T constant 16x32.
// f[15] = 1 doubles as the count for the mean.
//
// ws layout (floats):
//   [0, N*16)      f-sum accumulators (one 64B line per node)
//   flag (1) pad(7), coef (4*10), T (16*32)
// ---------------------------------------------------------------------------

__global__ void precompute_kernel(const float* __restrict__ Wq,
                                  const float* __restrict__ bq,
                                  const float* __restrict__ Wk,
                                  const float* __restrict__ bk,
                                  const float* __restrict__ Wv,
                                  const float* __restrict__ bv,
                                  const float* __restrict__ Wout,
                                  const int* __restrict__ ei,
                                  float* __restrict__ flag,
                                  float* __restrict__ coef,
                                  float* __restrict__ T) {
  __shared__ float sM[4][3][32];   // M_h[i][col] = sum_d Wv[i][h*32+d] Wout[h*32+d][col]
  __shared__ float sCv[4][32];     // cv_h[col]  = sum_d bv[h*32+d] Wout[h*32+d][col]
  int t = threadIdx.x;
  const float scale = 0.17677669529663687f;  // 1/sqrt(32)

  if (t == 0) {
    // int64 edge_index layout probe: odd 32-bit words of 8 random indices
    // in [0,1e5) are all zero iff the buffer is little-endian int64.
    int all_zero = 1;
    for (int i = 0; i < 8; ++i) all_zero &= (ei[2 * i + 1] == 0);
    flag[0] = all_zero ? 1.0f : 0.0f;
  }

  {
    int h = t >> 5, o = t & 31;
    float m0 = 0, m1 = 0, m2 = 0, cv = 0;
    for (int d = 0; d < 32; ++d) {
      int j = h * 32 + d;
      float w = Wout[j * 32 + o];
      m0 += Wv[0 * 128 + j] * w;
      m1 += Wv[1 * 128 + j] * w;
      m2 += Wv[2 * 128 + j] * w;
      cv += bv[j] * w;
    }
    sM[h][0][o] = m0;
    sM[h][1][o] = m1;
    sM[h][2][o] = m2;
    sCv[h][o] = cv;
  }

  if (t < 40) {
    int h = t / 10, j = t % 10;
    float acc = 0;
    for (int d = 0; d < 32; ++d) {
      int idx = h * 32 + d;
      float q0 = Wq[0 * 128 + idx], q1 = Wq[1 * 128 + idx], q2 = Wq[2 * 128 + idx];
      float k0 = Wk[0 * 128 + idx], k1 = Wk[1 * 128 + idx], k2 = Wk[2 * 128 + idx];
      float bqv = bq[idx], bkv = bk[idx];
      float v;
      switch (j) {
        case 0: v = q0 * k0; break;                 // x*x
        case 1: v = q1 * k1; break;                 // y*y
        case 2: v = q2 * k2; break;                 // z*z
        case 3: v = q0 * k1 + q1 * k0; break;       // x*y
        case 4: v = q0 * k2 + q2 * k0; break;       // x*z
        case 5: v = q1 * k2 + q2 * k1; break;       // y*z
        case 6: v = q0 * bkv + k0 * bqv; break;     // x
        case 7: v = q1 * bkv + k1 * bqv; break;     // y
        case 8: v = q2 * bkv + k2 * bqv; break;     // z
        default: v = bqv * bkv; break;              // const
      }
      acc += v;
    }
    coef[h * 10 + j] = acc * scale;
  }

  __syncthreads();

  for (int idx = t; idx < 512; idx += 128) {
    int j = idx >> 5, col = idx & 31;
    float v;
    if (j < 3)        v = sCv[j][col] - sCv[3][col];
    else if (j < 6)   v = sM[3][j - 3][col];
    else if (j < 15)  { int h = (j - 6) / 3, i = (j - 6) % 3; v = sM[h][i][col] - sM[3][i][col]; }
    else              v = sCv[3][col];
    T[idx] = v;
  }
}

__global__ void edge_kernel(const float* __restrict__ pos,
                            const int* __restrict__ ei, int E,
                            const float* __restrict__ flag,
                            const float* __restrict__ coef,
                            float* __restrict__ fsums) {
  const int lane = threadIdx.x & 31;
  const int group = (blockIdx.x * blockDim.x + threadIdx.x) >> 5;
  const int base = group * 32;
  if (base >= E) return;

  const int i64 = (flag[0] != 0.0f) ? 1 : 0;
  const int valid_n = min(32, E - base);
  const int e = base + lane;

  int c = 0;
  float rx = 0, ry = 0, rz = 0, a0 = 0, a1 = 0, a2 = 0;
  if (lane < valid_n) {
    int r, cc;
    if (i64) {
      r = ei[2 * (size_t)e];
      cc = ei[2 * ((size_t)E + e)];
    } else {
      r = ei[e];
      cc = ei[E + e];
    }
    c = cc;
    rx = pos[r * 3 + 0] - pos[cc * 3 + 0];
    ry = pos[r * 3 + 1] - pos[cc * 3 + 1];
    rz = pos[r * 3 + 2] - pos[cc * 3 + 2];
    float s[4];
#pragma unroll
    for (int h = 0; h < 4; ++h) {
      const float* cf = coef + h * 10;
      s[h] = cf[9] + rx * cf[6] + ry * cf[7] + rz * cf[8] + rx * rx * cf[0] +
             ry * ry * cf[1] + rz * rz * cf[2] + rx * ry * cf[3] +
             rx * rz * cf[4] + ry * rz * cf[5];
    }
    float mx = fmaxf(fmaxf(s[0], s[1]), fmaxf(s[2], s[3]));
    float e0 = __expf(s[0] - mx), e1 = __expf(s[1] - mx);
    float e2 = __expf(s[2] - mx), e3 = __expf(s[3] - mx);
    float inv = 1.0f / (e0 + e1 + e2 + e3);
    a0 = e0 * inv; a1 = e1 * inv; a2 = e2 * inv;   // a3 never needed
  }

  // component selectors: f[comp] = A * R,
  //   comp 0..2  -> a_comp           (A=a, R=1)
  //   comp 3..5  -> rel_{comp-3}     (A=1, R=rel)
  //   comp 6..14 -> a_h * rel_i      (h=(comp-6)/3, i=(comp-6)%3)
  //   comp 15    -> 1                (count)
  const int comp = lane & 15;
  int pa, pr;
  if (comp < 3)       { pa = comp;          pr = 3; }
  else if (comp < 6)  { pa = 3;             pr = comp - 3; }
  else if (comp < 15) { pa = (comp - 6) / 3; pr = (comp - 6) % 3; }
  else                { pa = 3;             pr = 3; }
  const int sub = lane >> 4;  // which of the 2 edges this half-slice handles

  for (int t2 = 0; t2 < valid_n; t2 += 2) {
    const int src = t2 + sub;
    float tx = __shfl(rx, src, 32);
    float ty = __shfl(ry, src, 32);
    float tz = __shfl(rz, src, 32);
    float b0 = __shfl(a0, src, 32);
    float b1 = __shfl(a1, src, 32);
    float b2 = __shfl(a2, src, 32);
    int   ct = __shfl(c,  src, 32);
    float A = (pa == 0) ? b0 : (pa == 1) ? b1 : (pa == 2) ? b2 : 1.0f;
    float R = (pr == 0) ? tx : (pr == 1) ? ty : (pr == 2) ? tz : 1.0f;
    if (src < valid_n)
      atomicAdd(&fsums[(size_t)ct * 16 + comp], A * R);
  }
}

__global__ void node_kernel(const float* __restrict__ fsums,
                            const float* __restrict__ T,
                            const float* __restrict__ bout,
                            const float* __restrict__ gamma,
                            const float* __restrict__ beta,
                            float* __restrict__ out, int N) {
  int tid = blockIdx.x * blockDim.x + threadIdx.x;
  int node = tid >> 5;
  int col = tid & 31;
  if (node >= N) return;

  float myf = fsums[(size_t)node * 16 + (col & 15)];
  float cnt = __shfl(myf, 15, 32);
  float invc = 1.0f / fmaxf(cnt, 1.0f);

  float acc = bout[col];
#pragma unroll
  for (int j = 0; j < 16; ++j) {
    float fj = __shfl(myf, j, 32);
    acc = fmaf(fj * invc, T[j * 32 + col], acc);
  }

  float sx = acc, sx2 = acc * acc;
#pragma unroll
  for (int off = 16; off >= 1; off >>= 1) {
    sx += __shfl_xor(sx, off);
    sx2 += __shfl_xor(sx2, off);
  }
  float mu = sx * (1.0f / 32.0f);
  float var = sx2 * (1.0f / 32.0f) - mu * mu;
  float inv = rsqrtf(var + LN_EPS);
  float y = (acc - mu) * inv * gamma[col] + beta[col];
  float o = y * (1.0f / (1.0f + __expf(-y)));  // SiLU
  out[(size_t)node * 32 + col] = o;
}

extern "C" void kernel_launch(void* const* d_in, const int* in_sizes, int n_in,
                              void* d_out, int out_size, void* d_ws, size_t ws_size,
                              hipStream_t stream) {
  const float* pos  = (const float*)d_in[0];
  const int*   ei   = (const int*)d_in[1];
  const float* Wq   = (const float*)d_in[2];
  const float* bq   = (const float*)d_in[3];
  const float* Wk   = (const float*)d_in[4];
  const float* bk   = (const float*)d_in[5];
  const float* Wv   = (const float*)d_in[6];
  const float* bv   = (const float*)d_in[7];
  const float* Wout = (const float*)d_in[8];
  const float* bout = (const float*)d_in[9];
  const float* gam  = (const float*)d_in[10];
  const float* bet  = (const float*)d_in[11];

  const int N = in_sizes[0] / 3;
  const int E = in_sizes[1] / 2;

  float* ws    = (float*)d_ws;
  float* fsums = ws;                           // N*16
  float* flag  = fsums + (size_t)N * 16;       // 1 (+7 pad)
  float* coef  = flag + 8;                     // 40
  float* T     = coef + 40;                    // 512

  hipMemsetAsync(d_ws, 0, (size_t)N * 16 * sizeof(float), stream);

  precompute_kernel<<<1, 128, 0, stream>>>(Wq, bq, Wk, bk, Wv, bv, Wout, ei,
                                           flag, coef, T);

  int edge_blocks = (E + 255) / 256;  // 8 groups of 32 edges per 256-block
  edge_kernel<<<edge_blocks, 256, 0, stream>>>(pos, ei, E, flag, coef, fsums);

  int node_blocks = (int)(((size_t)N * 32 + 255) / 256);
  node_kernel<<<node_blocks, 256, 0, stream>>>(fsums, T, bout, gam, bet,
                                               (float*)d_out, N);

  (void)n_in; (void)out_size; (void)ws_size;
}

// Round 4
// 144.669 us; speedup vs baseline: 1.3241x; 1.0065x over previous
//
#include <hip/hip_runtime.h>
#include <hip/hip_bf16.h>
#include <hip/hip_fp16.h>

#define LN_EPS 1e-5f

typedef _Float16 f16x2 __attribute__((ext_vector_type(2)));

__device__ __forceinline__ void pk_atomic_add(_Float16* p, float v0, float v1) {
  f16x2 v;
  v.x = (_Float16)v0;
  v.y = (_Float16)v1;
#if __has_builtin(__builtin_amdgcn_flat_atomic_fadd_v2f16)
  __builtin_amdgcn_flat_atomic_fadd_v2f16((f16x2*)p, v);
#else
  unsafeAtomicAdd((__half2*)p, *(__half2*)&v);
#endif
}

// ---------------------------------------------------------------------------
// Algebra: per-edge contribution to the (pre-mean) node feature is
//   contrib[col] = sum_h a_h (rel . M_h[col] + cv_h[col])
// linear in f = (a0,a1,a2, rx,ry,rz, a_h*rel_i for h<3, 1)  [16 dims]
// (sum_h a_h = 1 eliminates head 3). scatter-mean(contrib) = scatter-mean(f) @ T.
// f[15] = 1 doubles as the count. f accumulated in f16 via packed atomics
// (8 x 32-bit atomics/edge instead of 16) — error << 2% threshold.
//
// ws layout:
//   [0, N*16) _Float16   f-sum accumulators (32 B per node)
//   then floats: flag (1) pad(7), coef (4*10), T (16*32)
// ---------------------------------------------------------------------------

__global__ void precompute_kernel(const float* __restrict__ Wq,
                                  const float* __restrict__ bq,
                                  const float* __restrict__ Wk,
                                  const float* __restrict__ bk,
                                  const float* __restrict__ Wv,
                                  const float* __restrict__ bv,
                                  const float* __restrict__ Wout,
                                  const int* __restrict__ ei,
                                  float* __restrict__ flag,
                                  float* __restrict__ coef,
                                  float* __restrict__ T) {
  __shared__ float sM[4][3][32];
  __shared__ float sCv[4][32];
  int t = threadIdx.x;
  const float scale = 0.17677669529663687f;  // 1/sqrt(32)

  if (t == 0) {
    // int64 edge_index layout probe: odd 32-bit words of 8 random indices
    // in [0,1e5) are all zero iff the buffer is little-endian int64.
    int all_zero = 1;
    for (int i = 0; i < 8; ++i) all_zero &= (ei[2 * i + 1] == 0);
    flag[0] = all_zero ? 1.0f : 0.0f;
  }

  {
    int h = t >> 5, o = t & 31;
    float m0 = 0, m1 = 0, m2 = 0, cv = 0;
    for (int d = 0; d < 32; ++d) {
      int j = h * 32 + d;
      float w = Wout[j * 32 + o];
      m0 += Wv[0 * 128 + j] * w;
      m1 += Wv[1 * 128 + j] * w;
      m2 += Wv[2 * 128 + j] * w;
      cv += bv[j] * w;
    }
    sM[h][0][o] = m0;
    sM[h][1][o] = m1;
    sM[h][2][o] = m2;
    sCv[h][o] = cv;
  }

  if (t < 40) {
    int h = t / 10, j = t % 10;
    float acc = 0;
    for (int d = 0; d < 32; ++d) {
      int idx = h * 32 + d;
      float q0 = Wq[0 * 128 + idx], q1 = Wq[1 * 128 + idx], q2 = Wq[2 * 128 + idx];
      float k0 = Wk[0 * 128 + idx], k1 = Wk[1 * 128 + idx], k2 = Wk[2 * 128 + idx];
      float bqv = bq[idx], bkv = bk[idx];
      float v;
      switch (j) {
        case 0: v = q0 * k0; break;
        case 1: v = q1 * k1; break;
        case 2: v = q2 * k2; break;
        case 3: v = q0 * k1 + q1 * k0; break;
        case 4: v = q0 * k2 + q2 * k0; break;
        case 5: v = q1 * k2 + q2 * k1; break;
        case 6: v = q0 * bkv + k0 * bqv; break;
        case 7: v = q1 * bkv + k1 * bqv; break;
        case 8: v = q2 * bkv + k2 * bqv; break;
        default: v = bqv * bkv; break;
      }
      acc += v;
    }
    coef[h * 10 + j] = acc * scale;
  }

  __syncthreads();

  for (int idx = t; idx < 512; idx += 128) {
    int j = idx >> 5, col = idx & 31;
    float v;
    if (j < 3)        v = sCv[j][col] - sCv[3][col];
    else if (j < 6)   v = sM[3][j - 3][col];
    else if (j < 15)  { int h = (j - 6) / 3, i = (j - 6) % 3; v = sM[h][i][col] - sM[3][i][col]; }
    else              v = sCv[3][col];
    T[idx] = v;
  }
}

__device__ __forceinline__ void sel_comp(int comp, int& pa, int& pr) {
  if (comp < 3)       { pa = comp;           pr = 3; }
  else if (comp < 6)  { pa = 3;              pr = comp - 3; }
  else if (comp < 15) { pa = (comp - 6) / 3; pr = (comp - 6) % 3; }
  else                { pa = 3;              pr = 3; }
}

__global__ void edge_kernel(const float* __restrict__ pos,
                            const int* __restrict__ ei, int E,
                            const float* __restrict__ flag,
                            const float* __restrict__ coef,
                            _Float16* __restrict__ fsums) {
  const int lane = threadIdx.x & 31;
  const int group = (blockIdx.x * blockDim.x + threadIdx.x) >> 5;
  const int base = group * 32;
  if (base >= E) return;

  const int i64 = (flag[0] != 0.0f) ? 1 : 0;
  const int valid_n = min(32, E - base);
  const int e = base + lane;

  int c = 0;
  float rx = 0, ry = 0, rz = 0, a0 = 0, a1 = 0, a2 = 0;
  if (lane < valid_n) {
    int r, cc;
    if (i64) {
      r = ei[2 * (size_t)e];
      cc = ei[2 * ((size_t)E + e)];
    } else {
      r = ei[e];
      cc = ei[E + e];
    }
    c = cc;
    rx = pos[r * 3 + 0] - pos[cc * 3 + 0];
    ry = pos[r * 3 + 1] - pos[cc * 3 + 1];
    rz = pos[r * 3 + 2] - pos[cc * 3 + 2];
    float s[4];
#pragma unroll
    for (int h = 0; h < 4; ++h) {
      const float* cf = coef + h * 10;
      s[h] = cf[9] + rx * cf[6] + ry * cf[7] + rz * cf[8] + rx * rx * cf[0] +
             ry * ry * cf[1] + rz * rz * cf[2] + rx * ry * cf[3] +
             rx * rz * cf[4] + ry * rz * cf[5];
    }
    float mx = fmaxf(fmaxf(s[0], s[1]), fmaxf(s[2], s[3]));
    float e0 = __expf(s[0] - mx), e1 = __expf(s[1] - mx);
    float e2 = __expf(s[2] - mx), e3 = __expf(s[3] - mx);
    float inv = 1.0f / (e0 + e1 + e2 + e3);
    a0 = e0 * inv; a1 = e1 * inv; a2 = e2 * inv;   // a3 never needed
  }

  // 8 half2 slots per edge; 32 lanes handle 4 edges per iteration.
  const int pair = lane & 7;   // half2 slot: comps (2*pair, 2*pair+1)
  const int sub  = lane >> 3;  // which of the 4 in-flight edges
  int pa0, pr0, pa1, pr1;
  sel_comp(2 * pair, pa0, pr0);
  sel_comp(2 * pair + 1, pa1, pr1);

  for (int t2 = 0; t2 < valid_n; t2 += 4) {
    const int src = t2 + sub;
    float tx = __shfl(rx, src, 32);
    float ty = __shfl(ry, src, 32);
    float tz = __shfl(rz, src, 32);
    float b0 = __shfl(a0, src, 32);
    float b1 = __shfl(a1, src, 32);
    float b2 = __shfl(a2, src, 32);
    int   ct = __shfl(c,  src, 32);
    float A0 = (pa0 == 0) ? b0 : (pa0 == 1) ? b1 : (pa0 == 2) ? b2 : 1.0f;
    float R0 = (pr0 == 0) ? tx : (pr0 == 1) ? ty : (pr0 == 2) ? tz : 1.0f;
    float A1 = (pa1 == 0) ? b0 : (pa1 == 1) ? b1 : (pa1 == 2) ? b2 : 1.0f;
    float R1 = (pr1 == 0) ? tx : (pr1 == 1) ? ty : (pr1 == 2) ? tz : 1.0f;
    if (src < valid_n)
      pk_atomic_add(fsums + (size_t)ct * 16 + 2 * pair, A0 * R0, A1 * R1);
  }
}

__global__ void node_kernel(const _Float16* __restrict__ fsums,
                            const float* __restrict__ T,
                            const float* __restrict__ bout,
                            const float* __restrict__ gamma,
                            const float* __restrict__ beta,
                            float* __restrict__ out, int N) {
  int tid = blockIdx.x * blockDim.x + threadIdx.x;
  int node = tid >> 5;
  int col = tid & 31;
  if (node >= N) return;

  float myf = (float)fsums[(size_t)node * 16 + (col & 15)];
  float cnt = __shfl(myf, 15, 32);
  float invc = 1.0f / fmaxf(cnt, 1.0f);

  float acc = bout[col];
#pragma unroll
  for (int j = 0; j < 16; ++j) {
    float fj = __shfl(myf, j, 32);
    acc = fmaf(fj * invc, T[j * 32 + col], acc);
  }

  float sx = acc, sx2 = acc * acc;
#pragma unroll
  for (int off = 16; off >= 1; off >>= 1) {
    sx += __shfl_xor(sx, off);
    sx2 += __shfl_xor(sx2, off);
  }
  float mu = sx * (1.0f / 32.0f);
  float var = sx2 * (1.0f / 32.0f) - mu * mu;
  float inv = rsqrtf(var + LN_EPS);
  float y = (acc - mu) * inv * gamma[col] + beta[col];
  float o = y * (1.0f / (1.0f + __expf(-y)));  // SiLU
  out[(size_t)node * 32 + col] = o;
}

extern "C" void kernel_launch(void* const* d_in, const int* in_sizes, int n_in,
                              void* d_out, int out_size, void* d_ws, size_t ws_size,
                              hipStream_t stream) {
  const float* pos  = (const float*)d_in[0];
  const int*   ei   = (const int*)d_in[1];
  const float* Wq   = (const float*)d_in[2];
  const float* bq   = (const float*)d_in[3];
  const float* Wk   = (const float*)d_in[4];
  const float* bk   = (const float*)d_in[5];
  const float* Wv   = (const float*)d_in[6];
  const float* bv   = (const float*)d_in[7];
  const float* Wout = (const float*)d_in[8];
  const float* bout = (const float*)d_in[9];
  const float* gam  = (const float*)d_in[10];
  const float* bet  = (const float*)d_in[11];

  const int N = in_sizes[0] / 3;
  const int E = in_sizes[1] / 2;

  _Float16* fsums = (_Float16*)d_ws;                 // N*16 halves (N*32 B)
  float* tail = (float*)((char*)d_ws + (size_t)N * 32);
  float* flag = tail;            // 1 (+7 pad)
  float* coef = flag + 8;        // 40
  float* T    = coef + 40;       // 512

  hipMemsetAsync(d_ws, 0, (size_t)N * 16 * sizeof(_Float16), stream);

  precompute_kernel<<<1, 128, 0, stream>>>(Wq, bq, Wk, bk, Wv, bv, Wout, ei,
                                           flag, coef, T);

  int edge_blocks = (E + 255) / 256;  // 8 groups of 32 edges per 256-block
  edge_kernel<<<edge_blocks, 256, 0, stream>>>(pos, ei, E, flag, coef, fsums);

  int node_blocks = (int)(((size_t)N * 32 + 255) / 256);
  node_kernel<<<node_blocks, 256, 0, stream>>>(fsums, T, bout, gam, bet,
                                               (float*)d_out, N);

  (void)n_in; (void)out_size; (void)ws_size;
}